// Round 1
// 4431.637 us; speedup vs baseline: 1.2744x; 1.2744x over previous
//
#include <hip/hip_runtime.h>
#include <hip/hip_bf16.h>

// Problem constants
#define T_LEN 2048
#define E_DIM 300
#define H_DIM 512
#define G_DIM 2048   // 4*H
#define NBLK  32     // blocks per (direction,sentence) chain in recurrent kernel
#define UPB   16     // hidden units per block (H/NBLK)
#define TAG_OFF 0x40000000u

// Workspace layout (bytes).
// hb: (value,tag) pairs [2 dir][2 parity][2 sent][512] u64 = 32 KB.
// NOTE: hb bytes 16384..32767 (the d=1 half) overlap the head of x — safe:
// x is fully consumed by k_gemm before k_rnn's first store (same stream).
#define WS_H   0
#define WS_X   16384       // x: [2 sent][2048][300] f32 = 4,915,200 B
#define WS_GX  5242880     // gx: [d*2+s][2048 t][32 bb][4 q][16 ul] bf16 = 33,554,432 B

typedef float v2f __attribute__((ext_vector_type(2)));

__device__ __forceinline__ float sigmoid_fast(float x) {
    return 1.f / (1.f + __expf(-x));
}
__device__ __forceinline__ float tanh_fast(float x) {
    x = fminf(fmaxf(x, -15.f), 15.f);
    float e = __expf(-2.f * x);
    return (1.f - e) / (1.f + e);
}

// ---------------- k1: embedding gather ----------------
__global__ void k_gather(const int* __restrict__ sentA, const int* __restrict__ sentB,
                         const float* __restrict__ emb, float* __restrict__ x) {
    const int s = blockIdx.y;
    const int* sent = s ? sentB : sentA;
    const int t0 = blockIdx.x * 16;
    for (int idx = threadIdx.x; idx < 16 * 300; idx += 256) {
        int r = idx / 300, e = idx - r * 300;
        int t = t0 + r;
        int row = sent[t];
        x[((size_t)(s * 2048 + t)) * 300 + e] = emb[(size_t)row * 300 + e];
    }
}

// ---------------- k2: gx = x @ w_ih^T + (b_ih + b_hh), bf16, block-sliced layout ----------------
// grid (32 gi, 64 ti, 4 = d*2+s), block 256. Both tiles staged in LDS
// (coalesced global loads); K chunked 3x100.
__global__ __launch_bounds__(256) void k_gemm(const float* __restrict__ x,
                                              const float* __restrict__ w_ih,
                                              const float* __restrict__ b_ih,
                                              const float* __restrict__ b_hh,
                                              __hip_bfloat16* __restrict__ gx) {
    // stride 108 floats (432B, 16B-aligned rows; 108 mod 32 = 12 -> <=2-way banks)
    __shared__ float xs[32 * 108];
    __shared__ float ws_[64 * 108];
    const int gi = blockIdx.x, ti = blockIdx.y, z = blockIdx.z;
    const int d = z >> 1, s = z & 1;
    const int t0 = ti * 32, g0 = gi * 64;
    const int tg = threadIdx.x & 15, tt = threadIdx.x >> 4;
    const float* wbase = w_ih + (size_t)d * G_DIM * E_DIM;

    float acc[2][4];
#pragma unroll
    for (int j = 0; j < 2; ++j)
#pragma unroll
        for (int i = 0; i < 4; ++i) acc[j][i] = 0.f;

    for (int e0 = 0; e0 < 300; e0 += 100) {
        // stage x tile: 32 rows x 25 float4
        for (int idx = threadIdx.x; idx < 32 * 25; idx += 256) {
            int r = idx / 25, c = idx - r * 25;
            float4 v = *(const float4*)(x + ((size_t)(s * 2048 + t0 + r)) * 300 + e0 + c * 4);
            *(float4*)&xs[r * 108 + c * 4] = v;
        }
        // stage w tile: 64 rows x 25 float4
        for (int idx = threadIdx.x; idx < 64 * 25; idx += 256) {
            int r = idx / 25, c = idx - r * 25;
            float4 v = *(const float4*)(wbase + (size_t)(g0 + r) * 300 + e0 + c * 4);
            *(float4*)&ws_[r * 108 + c * 4] = v;
        }
        __syncthreads();

        for (int c = 0; c < 25; ++c) {
            float4 xv[2], wv[4];
#pragma unroll
            for (int j = 0; j < 2; ++j) xv[j] = *(const float4*)&xs[(tt + 16 * j) * 108 + c * 4];
#pragma unroll
            for (int i = 0; i < 4; ++i) wv[i] = *(const float4*)&ws_[(tg + 16 * i) * 108 + c * 4];
#pragma unroll
            for (int j = 0; j < 2; ++j)
#pragma unroll
                for (int i = 0; i < 4; ++i)
                    acc[j][i] += xv[j].x * wv[i].x + xv[j].y * wv[i].y +
                                 xv[j].z * wv[i].z + xv[j].w * wv[i].w;
        }
        __syncthreads();
    }

#pragma unroll
    for (int i = 0; i < 4; ++i) {
        int g = g0 + tg + 16 * i;
        float bias = b_ih[d * G_DIM + g] + b_hh[d * G_DIM + g];
        // block-sliced position: [bb][q][ul]
        int pos = ((g >> 4) & 31) * 64 + (g >> 9) * 16 + (g & 15);
#pragma unroll
        for (int j = 0; j < 2; ++j) {
            int t = t0 + tt + 16 * j;
            int tout = d ? (T_LEN - 1 - t) : t;   // backward run: time-reversed rows
            float v = acc[j][i] + bias;
            gx[(((size_t)(d * 2 + s) * T_LEN + tout) << 11) + pos] = __float2bfloat16(v);
        }
    }
}

// ---------------- k3: recurrent LSTM, 128 blocks = (2 dir x 2 sent x 32) ----------------
// One block per chain-slice: owns 16 hidden units x 4 gates of ONE (dir,sent)
// chain. h exchanged as (u32 step tag | fp32 value) u64 agent-scope atomics.
// Wave w polls ONLY its k-quarter of its own sentence (2 loads/lane,
// ping-pong pipelined), stages to LDS; B1; all waves read full h from LDS.
// Reduce identity tid = ul*16 + q*4 + sub keeps i/f/g/o in one 16-lane
// group -> shfl gather, no third barrier.
__global__ __launch_bounds__(256, 1) void k_rnn(const float* __restrict__ w_hh,
                                                const __hip_bfloat16* __restrict__ gx,
                                                unsigned long long* __restrict__ hb) {
    const int tid  = threadIdx.x;
    const int lane = tid & 63;
    const int w    = tid >> 6;          // wave index == gate row-block for matvec
    // reduce/gate-phase identity: tid = ul*16 + q*4 + sub
    const int sub  = tid & 3;
    const int q_g  = (tid >> 2) & 3;
    const int ul_g = tid >> 4;
    const int bid = blockIdx.x;         // (d*2+s)*32 + bb
    const int d  = bid >> 6;
    const int s  = (bid >> 5) & 1;
    const int bb = bid & 31;

    // persistent weights, row-paired: wreg2[r2][kb] = { W[w*512+bb*16+2r2][k], W[+1][k] }
    v2f wreg2[8][8];
#pragma unroll
    for (int r2 = 0; r2 < 8; ++r2)
#pragma unroll
        for (int kb = 0; kb < 8; ++kb) {
            const float* wp = w_hh + ((size_t)d * G_DIM + w * 512 + bb * 16 + 2 * r2) * H_DIM
                            + kb * 64 + lane;
            v2f t2; t2.x = wp[0]; t2.y = wp[H_DIM];
            wreg2[r2][kb] = t2;
        }

    __shared__ float hlds[H_DIM];       // staged h for this sentence (2 KB)
    __shared__ float pacc[64 * 68];     // 64 rows (ul*4+q) x 64 lanes (+4 pad) ~17 KB

    float c_state = 0.f;

    // h_0 = 0, tag TAG_OFF, parity 0 (published by the 16 state-carrier threads)
    if ((lane & 15) == 0) {
        __hip_atomic_store(&hb[((size_t)(d * 2 + 0) * 2 + s) * H_DIM + bb * UPB + ul_g],
                           (unsigned long long)TAG_OFF << 32,
                           __ATOMIC_RELAXED, __HIP_MEMORY_SCOPE_AGENT);
    }

    // poll indices: wave w owns k-quarter [w*128, w*128+128) of its sentence
    const int i0 = w * 128 + lane;
    const int i1 = i0 + 64;

    for (int t = 0; t < T_LEN; ++t) {
        const int p  = t & 1;
        const int pn = p ^ 1;

        // prefetch this thread's gate input (overlaps the poll)
        float gxv = (float)gx[(((size_t)(d * 2 + s) * T_LEN + t) << 11)
                              + bb * 64 + q_g * 16 + ul_g];

        unsigned long long* hbp = hb + ((size_t)(d * 2 + p) * 2 + s) * H_DIM;
        const unsigned int tag = TAG_OFF + (unsigned int)t;
        unsigned long long a0, a1, b0, b1;

#define LDH(X) __hip_atomic_load(&hbp[X], __ATOMIC_RELAXED, __HIP_MEMORY_SCOPE_AGENT)
        a0 = LDH(i0); a1 = LDH(i1);
        int guard = 0;
        for (;;) {
            b0 = LDH(i0); b1 = LDH(i1);
            bool okA = ((unsigned int)(a0 >> 32) == tag) & ((unsigned int)(a1 >> 32) == tag);
            if (__all(okA)) break;
            if (++guard > (1 << 20)) break;
            a0 = LDH(i0); a1 = LDH(i1);
            bool okB = ((unsigned int)(b0 >> 32) == tag) & ((unsigned int)(b1 >> 32) == tag);
            if (__all(okB)) { a0 = b0; a1 = b1; break; }
            if (++guard > (1 << 20)) break;
        }
#undef LDH

        // stage this wave's quarter into LDS
        hlds[i0] = __uint_as_float((unsigned int)a0);
        hlds[i1] = __uint_as_float((unsigned int)a1);
        __syncthreads();   // B1: full h visible to all waves

        // load full h fragment for this lane
        float hv[8];
#pragma unroll
        for (int kb = 0; kb < 8; ++kb)
            hv[kb] = hlds[kb * 64 + lane];

        // matvec partials: 8 row-pairs per lane, packed fp32 FMA (64 v2f)
        v2f acc2[8];
#pragma unroll
        for (int r2 = 0; r2 < 8; ++r2) acc2[r2] = (v2f)(0.f);
#pragma unroll
        for (int kb = 0; kb < 8; ++kb) {
            float h0 = hv[kb];
            v2f h2; h2.x = h0; h2.y = h0;
#pragma unroll
            for (int r2 = 0; r2 < 8; ++r2)
                acc2[r2] += wreg2[r2][kb] * h2;
        }

        // publish partials: physical row index = ul*4 + q (q = this wave w)
#pragma unroll
        for (int r2 = 0; r2 < 8; ++r2) {
            pacc[((2 * r2 + 0) * 4 + w) * 68 + lane] = acc2[r2].x;
            pacc[((2 * r2 + 1) * 4 + w) * 68 + lane] = acc2[r2].y;
        }
        __syncthreads();   // B2

        // reduce row r_phys = ul*4 + q = tid>>2: 4 threads x 16 values
        const float4* pr = (const float4*)&pacc[(tid >> 2) * 68 + sub * 16];
        float4 sv = pr[0];
#pragma unroll
        for (int j2 = 1; j2 < 4; ++j2) {
            float4 q4 = pr[j2];
            sv.x += q4.x; sv.y += q4.y; sv.z += q4.z; sv.w += q4.w;
        }
        float v = (sv.x + sv.y) + (sv.z + sv.w);
        v += __shfl_xor(v, 1, 64);
        v += __shfl_xor(v, 2, 64);
        v += gxv;
        float act = (q_g == 2) ? tanh_fast(v) : sigmoid_fast(v);

        // gather i/f/g/o within the 16-lane group (lanes g0l+4q), update, publish
        const int g0l = lane & ~15;
        float si = __shfl(act, g0l + 0,  64);
        float sf = __shfl(act, g0l + 4,  64);
        float tg = __shfl(act, g0l + 8,  64);
        float so = __shfl(act, g0l + 12, 64);
        if ((lane & 15) == 0) {
            c_state = sf * c_state + si * tg;
            float h_new = so * tanh_fast(c_state);
            unsigned long long pkt = ((unsigned long long)(TAG_OFF + (unsigned int)(t + 1)) << 32)
                                   | (unsigned long long)__float_as_uint(h_new);
            __hip_atomic_store(&hb[((size_t)(d * 2 + pn) * 2 + s) * H_DIM + bb * UPB + ul_g],
                               pkt, __ATOMIC_RELAXED, __HIP_MEMORY_SCOPE_AGENT);
        }
        // pacc/hlds WAR across steps protected by B1/B2:
        // any wave passing poll(t+1) implies ALL this block's waves published
        // step t (each wave publishes 4 of the 16 units), which in program
        // order follows their hlds/pacc reads for step t.
    }
}

// ---------------- k4: head ----------------
__global__ __launch_bounds__(512) void k_head(const unsigned long long* __restrict__ hb,
                                              const float* __restrict__ bi_w,
                                              const float* __restrict__ bi_b,
                                              const float* __restrict__ blA,
                                              const float* __restrict__ blB,
                                              const float* __restrict__ bl_b,
                                              const float* __restrict__ out_w,
                                              const float* __restrict__ out_b,
                                              float* __restrict__ out) {
    __shared__ float enc[2][512];
    __shared__ float red[8];
    const int tid = threadIdx.x;
    const float bw0 = bi_w[0], bw1 = bi_w[1], bib = bi_b[0];
    {
        int u = tid;
        // final h (t=2048) lives in parity 0
        float hfA = __uint_as_float((unsigned int)hb[((0 * 2 + 0) * 2 + 0) * 512 + u]);
        float hbA = __uint_as_float((unsigned int)hb[((1 * 2 + 0) * 2 + 0) * 512 + u]);
        float hfB = __uint_as_float((unsigned int)hb[((0 * 2 + 0) * 2 + 1) * 512 + u]);
        float hbB = __uint_as_float((unsigned int)hb[((1 * 2 + 0) * 2 + 1) * 512 + u]);
        enc[0][u] = bw0 * hfA + bw1 * hbA + bib;
        enc[1][u] = bw0 * hfB + bw1 * hbB + bib;
    }
    __syncthreads();
    const int j = tid;
    float acc = bl_b[j];
#pragma unroll 4
    for (int u = 0; u < 512; ++u)
        acc += enc[0][u] * blA[u * 512 + j] + enc[1][u] * blB[u * 512 + j];
    float contrib = tanh_fast(acc) * out_w[j];
#pragma unroll
    for (int m = 1; m < 64; m <<= 1) contrib += __shfl_xor(contrib, m, 64);
    if ((tid & 63) == 0) red[tid >> 6] = contrib;
    __syncthreads();
    if (tid == 0) {
        float s = 0.f;
#pragma unroll
        for (int i = 0; i < 8; ++i) s += red[i];
        s += out_b[0];
        out[0] = sigmoid_fast(s);
    }
}

extern "C" void kernel_launch(void* const* d_in, const int* in_sizes, int n_in,
                              void* d_out, int out_size, void* d_ws, size_t ws_size,
                              hipStream_t stream) {
    const int*   sentA = (const int*)d_in[0];
    const int*   sentB = (const int*)d_in[1];
    // d_in[2] = hidden (unused by forward)
    const float* emb   = (const float*)d_in[3];
    const float* w_ih  = (const float*)d_in[4];
    const float* w_hh  = (const float*)d_in[5];
    const float* b_ih  = (const float*)d_in[6];
    const float* b_hh  = (const float*)d_in[7];
    const float* bi_w  = (const float*)d_in[8];
    const float* bi_b  = (const float*)d_in[9];
    const float* blA   = (const float*)d_in[10];
    const float* blB   = (const float*)d_in[11];
    const float* bl_b  = (const float*)d_in[12];
    const float* out_w = (const float*)d_in[13];
    const float* out_b = (const float*)d_in[14];
    float* out = (float*)d_out;

    char* ws = (char*)d_ws;
    unsigned long long* hbf = (unsigned long long*)(ws + WS_H);
    float*              x   = (float*)(ws + WS_X);
    __hip_bfloat16*     gx  = (__hip_bfloat16*)(ws + WS_GX);

    k_gather<<<dim3(128, 2), 256, 0, stream>>>(sentA, sentB, emb, x);
    k_gemm<<<dim3(32, 64, 4), 256, 0, stream>>>(x, w_ih, b_ih, b_hh, gx);
    k_rnn<<<dim3(128), 256, 0, stream>>>(w_hh, gx, hbf);
    k_head<<<dim3(1), 512, 0, stream>>>(hbf, bi_w, bi_b, blA, blB, bl_b, out_w, out_b, out);
}